// Round 15
// baseline (150.152 us; speedup 1.0000x reference)
//
#include <hip/hip_runtime.h>

#define NBINS     (640 * 640)
#define REGIONS   256
#define RBINS     1600                 // bins per region (range-based)
#define P1_BLOCK  512
#define P1_K      4                    // points per thread, register-held
#define P1_PTS    (P1_BLOCK * P1_K)    // 2048
#define P2_BLOCK  1024
#define NBLK_MAX  3968

typedef float f4 __attribute__((ext_vector_type(4)));

// Exact reference arithmetic: IEEE f32 div/mul, trunc cast. Returns bin in
// [0, NBINS) or -1 (fails mask, or segment_max OOB-drop at the x-boundary).
// Deterministic: recomputing on the same payload yields the same bin.
__device__ __forceinline__ int point_bin(f4 p, float l00, float l01, float l10,
                                         float l11, float dx, float dy,
                                         float fs0, float fs1, int s0) {
    bool m = (p.x > l00) & (p.x < l01) & (p.y > l10) & (p.y < l11);
    if (!m) return -1;
    int xi = (int)((p.x - l00) / dx * fs0);
    int yi = (int)((p.y - l10) / dy * fs1);
    int t = xi * s0 + yi;            // mask => xi,yi >= 0; max fits i32
    return (t < NBINS) ? t : -1;
}

__device__ __forceinline__ void dev_atomic_max_filtered(float* b, f4 p, f4 cur) {
    if (p.x > cur.x) atomicMax((int*)&b[0], __float_as_int(p.x));
    if (p.y > cur.y) atomicMax((int*)&b[1], __float_as_int(p.y));
    if (p.z > cur.z) atomicMax((int*)&b[2], __float_as_int(p.z));
    if (p.w > cur.w) atomicMax((int*)&b[3], __float_as_int(p.w));
}

// ---------- Stream kernel: pure pc -> pc_masked pass (no LDS/atomics) ------
// Dedicated single-purpose pipeline; should run at near-copy rate. Also
// warms L3 with pc for the bucketing pass that follows.
__global__ __launch_bounds__(256) void pfe_stream(
    const f4* __restrict__ pc, const float* __restrict__ lim,
    f4* __restrict__ pc_masked, int n) {
    const float l00 = lim[0], l01 = lim[1], l10 = lim[2], l11 = lim[3];
    const f4 zero = {0.f, 0.f, 0.f, 0.f};

    const int stride = gridDim.x * blockDim.x;
    int base = blockIdx.x * blockDim.x + threadIdx.x;
    for (; base < n; base += 4 * stride) {
        f4 p[4]; bool live[4];
        #pragma unroll
        for (int u = 0; u < 4; ++u) {
            const int i = base + u * stride;
            live[u] = i < n;
            p[u] = live[u] ? pc[i] : zero;
        }
        #pragma unroll
        for (int u = 0; u < 4; ++u) {
            const bool m = (p[u].x > l00) & (p[u].x < l01) &
                           (p[u].y > l10) & (p[u].y < l11);
            if (live[u])
                __builtin_nontemporal_store(m ? p[u] : zero,
                                            &pc_masked[base + u * stride]);
        }
    }
}

// ---- Pass 1 (lean): bucket-only — read pc (L3-hot), write bvals + table ---
// ONE device atomic per block; ONE LDS atomic per point (rank capture).
// Direct-from-register bucket writes into the block's dense window (L2
// write-combines). No pc_masked store here.
__global__ __launch_bounds__(P1_BLOCK) void pfe_pass1(
    const f4* __restrict__ pc, const float* __restrict__ lim,
    const int* __restrict__ size, float* __restrict__ seg,
    f4* __restrict__ bvals, unsigned* __restrict__ table,
    unsigned* __restrict__ cursor, unsigned cap, int n, int nblk) {
    __shared__ unsigned hist[REGIONS], lstart[REGIONS + 1];
    __shared__ unsigned sgbase;

    const float l00 = lim[0], l01 = lim[1], l10 = lim[2], l11 = lim[3];
    const int s0 = size[0];
    const float fs0 = (float)size[0], fs1 = (float)size[1];
    const float dx = l01 - l00, dy = l11 - l10;
    const int tid = threadIdx.x;

    if (tid < REGIONS) hist[tid] = 0;
    __syncthreads();

    const int base = blockIdx.x * P1_PTS;

    // Phase A: load K points into registers, bin, LDS histogram with rank
    // capture. Points persist in registers.
    f4  p[P1_K];
    int bin[P1_K];
    unsigned rank[P1_K];
    #pragma unroll
    for (int k = 0; k < P1_K; ++k) {
        int i = base + k * P1_BLOCK + tid;
        p[k] = (i < n) ? pc[i] : (f4){l00, l10, 0.f, 0.f};  // fails mask
    }
    #pragma unroll
    for (int k = 0; k < P1_K; ++k) {
        bin[k] = point_bin(p[k], l00, l01, l10, l11, dx, dy, fs0, fs1, s0);
        if (bin[k] >= 0)
            rank[k] = atomicAdd(&hist[(unsigned)bin[k] / RBINS], 1u);
    }
    __syncthreads();

    // Single-wave exclusive scan of hist[256] (64 lanes x 4) — 2 barriers.
    if (tid < 64) {
        unsigned v[4], run = 0;
        #pragma unroll
        for (int j = 0; j < 4; ++j) { v[j] = run; run += hist[tid * 4 + j]; }
        unsigned x = run;
        #pragma unroll
        for (int o = 1; o < 64; o <<= 1) {
            unsigned t = __shfl_up(x, o, 64);
            if (tid >= o) x += t;
        }
        unsigned excl = x - run;          // exclusive across lanes
        #pragma unroll
        for (int j = 0; j < 4; ++j) lstart[tid * 4 + j] = excl + v[j];
        if (tid == 63) {
            lstart[REGIONS] = x;          // block total
            // SINGLE reservation per block — no per-region cursor convoy.
            sgbase = atomicAdd(cursor, x);
        }
    }
    __syncthreads();

    const unsigned gbase = sgbase;

    // Region-major boundary table for pass 2 (global slot indices).
    for (int r = tid; r <= REGIONS; r += P1_BLOCK)
        table[(size_t)r * nblk + blockIdx.x] = gbase + lstart[r];

    // Phase C: write bucket slots directly from registers (dense window,
    // L2 write-combined).
    #pragma unroll
    for (int k = 0; k < P1_K; ++k) {
        if (bin[k] >= 0) {
            unsigned g = gbase + lstart[(unsigned)bin[k] / RBINS] + rank[k];
            if (g < cap) {
                bvals[g] = p[k];
            } else {
                // Capacity overflow: filtered device atomics (merged by P2).
                float* b = seg + (size_t)bin[k] * 4;
                dev_atomic_max_filtered(b, p[k], *(const f4*)b);
            }
        }
    }
}

// ---------------- Pass 2: exclusive gather per region ----------------
// Block r owns bins [r*RBINS, (r+1)*RBINS). Boundary rows r and r+1 are
// staged into LDS with dense coalesced loads; 8-lane groups then consume
// each block-run with coalesced 16B-per-lane reads.
__global__ __launch_bounds__(P2_BLOCK) void pfe_pass2(
    const f4* __restrict__ bvals, const unsigned* __restrict__ table,
    const float* __restrict__ lim, const int* __restrict__ size,
    int nblk, unsigned cap, float* __restrict__ seg) {
    const int r = blockIdx.x;
    const int b0 = r * RBINS;
    const int tid = threadIdx.x;

    const float l00 = lim[0], l01 = lim[1], l10 = lim[2], l11 = lim[3];
    const int s0 = size[0];
    const float fs0 = (float)size[0], fs1 = (float)size[1];
    const float dx = l01 - l00, dy = l11 - l10;

    __shared__ int tile[RBINS * 4];              // fp32 bits, all >= 0
    __shared__ unsigned sst[NBLK_MAX], sen[NBLK_MAX];

    for (int j = tid; j < RBINS * 4; j += P2_BLOCK) tile[j] = 0;
    const unsigned* row0 = table + (size_t)r * nblk;
    const unsigned* row1 = row0 + nblk;
    for (int b = tid; b < nblk; b += P2_BLOCK) {
        sst[b] = row0[b];
        sen[b] = row1[b];
    }
    __syncthreads();

    const int grp = tid >> 3, l8 = tid & 7, ngrp = P2_BLOCK / 8;
    for (int b = grp; b < nblk; b += ngrp) {
        unsigned s = sst[b], e = sen[b];
        if (s > cap) s = cap;
        if (e > cap) e = cap;
        for (unsigned g = s + l8; g < e; g += 8) {
            f4 v = bvals[g];
            // Recompute bin from payload (bit-identical arithmetic).
            int bin = point_bin(v, l00, l01, l10, l11, dx, dy, fs0, fs1, s0);
            int t = (bin - b0) * 4;
            // Non-negative floats order as their int bits; skip non-positives.
            if (v.x > 0.f) atomicMax(&tile[t + 0], __float_as_int(v.x));
            if (v.y > 0.f) atomicMax(&tile[t + 1], __float_as_int(v.y));
            if (v.z > 0.f) atomicMax(&tile[t + 2], __float_as_int(v.z));
            if (v.w > 0.f) atomicMax(&tile[t + 3], __float_as_int(v.w));
        }
    }
    __syncthreads();

    // Merge with seg (holds only rare overflow-path maxes, else zeros).
    for (int j = tid; j < RBINS; j += P2_BLOCK) {
        f4 s = *(const f4*)(seg + (size_t)(b0 + j) * 4);
        f4 o;
        o.x = fmaxf(__int_as_float(tile[j * 4 + 0]), s.x);
        o.y = fmaxf(__int_as_float(tile[j * 4 + 1]), s.y);
        o.z = fmaxf(__int_as_float(tile[j * 4 + 2]), s.z);
        o.w = fmaxf(__int_as_float(tile[j * 4 + 3]), s.w);
        *(f4*)(seg + (size_t)(b0 + j) * 4) = o;
    }
}

// ---------------- Fallback (round-4 kernel, proven) ----------------
__global__ __launch_bounds__(256) void pfe_scatter_kernel(
    const f4* __restrict__ pc, const float* __restrict__ lim,
    const int* __restrict__ size, f4* __restrict__ pc_masked,
    float* __restrict__ seg, int n) {
    const float l00 = lim[0], l01 = lim[1], l10 = lim[2], l11 = lim[3];
    const int s0 = size[0];
    const float fs0 = (float)size[0], fs1 = (float)size[1];
    const float dx = l01 - l00, dy = l11 - l10;
    const f4 zero = {0.f, 0.f, 0.f, 0.f};

    const int stride = gridDim.x * blockDim.x;
    int base = blockIdx.x * blockDim.x + threadIdx.x;
    for (; base < n; base += 4 * stride) {
        f4 p[4]; bool live[4]; int bin[4];
        #pragma unroll
        for (int u = 0; u < 4; ++u) {
            const int i = base + u * stride;
            live[u] = i < n;
            p[u] = live[u] ? pc[i] : (f4){l00, l10, 0.f, 0.f};
        }
        #pragma unroll
        for (int u = 0; u < 4; ++u) {
            bin[u] = point_bin(p[u], l00, l01, l10, l11, dx, dy, fs0, fs1, s0);
            if (live[u])
                __builtin_nontemporal_store(bin[u] >= 0 ? p[u] : zero,
                                            &pc_masked[base + u * stride]);
        }
        f4 cur[4];
        #pragma unroll
        for (int u = 0; u < 4; ++u)
            if (bin[u] >= 0) cur[u] = *(const f4*)(seg + (size_t)bin[u] * 4);
        #pragma unroll
        for (int u = 0; u < 4; ++u) {
            if (bin[u] < 0) continue;
            dev_atomic_max_filtered(seg + (size_t)bin[u] * 4, p[u], cur[u]);
        }
    }
}

extern "C" void kernel_launch(void* const* d_in, const int* in_sizes, int n_in,
                              void* d_out, int out_size, void* d_ws, size_t ws_size,
                              hipStream_t stream) {
    const f4*    pc  = (const f4*)d_in[0];
    const float* lim = (const float*)d_in[1];
    const int*   sz  = (const int*)d_in[2];

    const int n = in_sizes[0] / 4;             // 8,000,000 points
    float* out       = (float*)d_out;
    float* pc_masked = out;                    // n*4 floats
    float* seg       = out + (size_t)n * 4;    // NBINS*4 floats

    (void)hipMemsetAsync(seg, 0, (size_t)NBINS * 4 * sizeof(float), stream);

    const int nblk = (n + P1_PTS - 1) / P1_PTS;          // 3907
    const size_t tbl_bytes =
        (size_t)(REGIONS + 1) * nblk * sizeof(unsigned); // ~4.02 MB

    // Workspace: bvals f4[cap] | table u32[(REGIONS+1)*nblk] | cursor u32
    long long cap = 0;
    if (ws_size > tbl_bytes + 64)
        cap = (long long)((ws_size - tbl_bytes - 64) / sizeof(f4));
    if (cap > 8100000) cap = 8100000;          // never need more than n

    if (cap >= 6500000 && nblk <= NBLK_MAX) {  // expected masked ~5.43M
        f4*       bvals  = (f4*)d_ws;
        unsigned* table  = (unsigned*)(bvals + cap);
        unsigned* cursor = table + (size_t)(REGIONS + 1) * nblk;

        (void)hipMemsetAsync(cursor, 0, sizeof(unsigned), stream);

        // 1) pure stream (also warms L3 with pc), 2) lean bucket, 3) gather.
        pfe_stream<<<2048, 256, 0, stream>>>(pc, lim, (f4*)pc_masked, n);
        pfe_pass1<<<nblk, P1_BLOCK, 0, stream>>>(
            pc, lim, sz, seg, bvals, table, cursor, (unsigned)cap, n, nblk);
        pfe_pass2<<<REGIONS, P2_BLOCK, 0, stream>>>(
            bvals, table, lim, sz, nblk, (unsigned)cap, seg);
    } else {
        pfe_scatter_kernel<<<2048, 256, 0, stream>>>(
            pc, lim, sz, (f4*)pc_masked, seg, n);
    }
}

// Round 16
// 99.705 us; speedup vs baseline: 1.5060x; 1.5060x over previous
//
#include <hip/hip_runtime.h>

#define NBINS     (640 * 640)
#define REGIONS   256
#define RBINS     1600                 // bins per region (range-based)
#define P1_BLOCK  512
#define P1_K      8                    // points per thread, register-held
#define P1_PTS    (P1_BLOCK * P1_K)    // 4096
#define P2_BLOCK  1024
#define NBLK_MAX  1984

typedef float f4 __attribute__((ext_vector_type(4)));

// Exact reference arithmetic: IEEE f32 div/mul, trunc cast. Returns bin in
// [0, NBINS) or -1 (fails mask, or segment_max OOB-drop at the x-boundary).
// Deterministic: recomputing on the same payload yields the same bin.
__device__ __forceinline__ int point_bin(f4 p, float l00, float l01, float l10,
                                         float l11, float dx, float dy,
                                         float fs0, float fs1, int s0) {
    bool m = (p.x > l00) & (p.x < l01) & (p.y > l10) & (p.y < l11);
    if (!m) return -1;
    int xi = (int)((p.x - l00) / dx * fs0);
    int yi = (int)((p.y - l10) / dy * fs1);
    int t = xi * s0 + yi;            // mask => xi,yi >= 0; max fits i32
    return (t < NBINS) ? t : -1;
}

__device__ __forceinline__ void dev_atomic_max_filtered(float* b, f4 p, f4 cur) {
    if (p.x > cur.x) atomicMax((int*)&b[0], __float_as_int(p.x));
    if (p.y > cur.y) atomicMax((int*)&b[1], __float_as_int(p.y));
    if (p.z > cur.z) atomicMax((int*)&b[2], __float_as_int(p.z));
    if (p.w > cur.w) atomicMax((int*)&b[3], __float_as_int(p.w));
}

// ---- Pass 1: fused stream + bucket, K=8 register-held, stagingless --------
// ONE device atomic per block; ONE LDS atomic per point (rank capture).
// Direct-from-register bucket writes into the block's dense window (L2
// write-combines — verified round 14: WRITE_SIZE stayed at ideal).
__global__ __launch_bounds__(P1_BLOCK) void pfe_pass1(
    const f4* __restrict__ pc, const float* __restrict__ lim,
    const int* __restrict__ size, f4* __restrict__ pc_masked,
    float* __restrict__ seg, f4* __restrict__ bvals,
    unsigned* __restrict__ table, unsigned* __restrict__ cursor,
    unsigned cap, int n, int nblk) {
    __shared__ unsigned hist[REGIONS], lstart[REGIONS + 1];
    __shared__ unsigned sgbase;

    const float l00 = lim[0], l01 = lim[1], l10 = lim[2], l11 = lim[3];
    const int s0 = size[0];
    const float fs0 = (float)size[0], fs1 = (float)size[1];
    const float dx = l01 - l00, dy = l11 - l10;
    const f4 zero = {0.f, 0.f, 0.f, 0.f};
    const int tid = threadIdx.x;

    if (tid < REGIONS) hist[tid] = 0;
    __syncthreads();

    const int base = blockIdx.x * P1_PTS;

    // Phase A: load K points into registers (8 outstanding), mask/bin,
    // nt-stream pc_masked, LDS histogram with rank capture.
    f4  p[P1_K];
    int bin[P1_K];
    unsigned rank[P1_K];
    #pragma unroll
    for (int k = 0; k < P1_K; ++k) {
        int i = base + k * P1_BLOCK + tid;
        p[k] = (i < n) ? pc[i] : (f4){l00, l10, 0.f, 0.f};  // fails mask
    }
    #pragma unroll
    for (int k = 0; k < P1_K; ++k) {
        int i = base + k * P1_BLOCK + tid;
        bin[k] = point_bin(p[k], l00, l01, l10, l11, dx, dy, fs0, fs1, s0);
        if (i < n)
            __builtin_nontemporal_store(bin[k] >= 0 ? p[k] : zero,
                                        &pc_masked[i]);
        if (bin[k] >= 0)
            rank[k] = atomicAdd(&hist[(unsigned)bin[k] / RBINS], 1u);
    }
    __syncthreads();

    // Single-wave exclusive scan of hist[256] (64 lanes x 4) — 2 barriers.
    if (tid < 64) {
        unsigned v[4], run = 0;
        #pragma unroll
        for (int j = 0; j < 4; ++j) { v[j] = run; run += hist[tid * 4 + j]; }
        unsigned x = run;
        #pragma unroll
        for (int o = 1; o < 64; o <<= 1) {
            unsigned t = __shfl_up(x, o, 64);
            if (tid >= o) x += t;
        }
        unsigned excl = x - run;          // exclusive across lanes
        #pragma unroll
        for (int j = 0; j < 4; ++j) lstart[tid * 4 + j] = excl + v[j];
        if (tid == 63) {
            lstart[REGIONS] = x;          // block total
            // SINGLE reservation per block — no per-region cursor convoy.
            sgbase = atomicAdd(cursor, x);
        }
    }
    __syncthreads();

    const unsigned gbase = sgbase;

    // Region-major boundary table for pass 2 (global slot indices).
    for (int r = tid; r <= REGIONS; r += P1_BLOCK)
        table[(size_t)r * nblk + blockIdx.x] = gbase + lstart[r];

    // Phase C: write bucket slots directly from registers (dense window,
    // L2 write-combined).
    #pragma unroll
    for (int k = 0; k < P1_K; ++k) {
        if (bin[k] >= 0) {
            unsigned g = gbase + lstart[(unsigned)bin[k] / RBINS] + rank[k];
            if (g < cap) {
                bvals[g] = p[k];
            } else {
                // Capacity overflow (statistically never): filtered device
                // atomics into seg; pass 2 merges. Works even on poisoned
                // seg (0xAA.. bit pattern is a tiny NEGATIVE float, and the
                // int-compare of any positive value beats it).
                float* b = seg + (size_t)bin[k] * 4;
                dev_atomic_max_filtered(b, p[k], *(const f4*)b);
            }
        }
    }
}

// ---------------- Pass 2: exclusive gather per region ----------------
// Block r owns bins [r*RBINS, (r+1)*RBINS). No-overflow case (normal):
// plain-store max(tile,0) — seg needs NO zero-init (tile starts at 0).
// Overflow case: merge with seg via fmaxf (idempotent across replays,
// safe on poisoned seg: 0xAA.. is a tiny negative float).
__global__ __launch_bounds__(P2_BLOCK) void pfe_pass2(
    const f4* __restrict__ bvals, const unsigned* __restrict__ table,
    const float* __restrict__ lim, const int* __restrict__ size,
    const unsigned* __restrict__ cursor, int nblk, unsigned cap,
    float* __restrict__ seg) {
    const int r = blockIdx.x;
    const int b0 = r * RBINS;
    const int tid = threadIdx.x;

    const float l00 = lim[0], l01 = lim[1], l10 = lim[2], l11 = lim[3];
    const int s0 = size[0];
    const float fs0 = (float)size[0], fs1 = (float)size[1];
    const float dx = l01 - l00, dy = l11 - l10;

    __shared__ int tile[RBINS * 4];              // fp32 bits, all >= 0
    __shared__ unsigned sst[NBLK_MAX], sen[NBLK_MAX];

    for (int j = tid; j < RBINS * 4; j += P2_BLOCK) tile[j] = 0;
    const unsigned* row0 = table + (size_t)r * nblk;
    const unsigned* row1 = row0 + nblk;
    for (int b = tid; b < nblk; b += P2_BLOCK) {
        sst[b] = row0[b];
        sen[b] = row1[b];
    }
    const bool ovf = (*cursor > cap);            // uniform scalar load
    __syncthreads();

    const int grp = tid >> 3, l8 = tid & 7, ngrp = P2_BLOCK / 8;
    for (int b = grp; b < nblk; b += ngrp) {
        unsigned s = sst[b], e = sen[b];
        if (s > cap) s = cap;
        if (e > cap) e = cap;
        for (unsigned g = s + l8; g < e; g += 8) {
            f4 v = bvals[g];
            // Recompute bin from payload (bit-identical arithmetic).
            int bin = point_bin(v, l00, l01, l10, l11, dx, dy, fs0, fs1, s0);
            int t = (bin - b0) * 4;
            // Non-negative floats order as their int bits; skip non-positives.
            if (v.x > 0.f) atomicMax(&tile[t + 0], __float_as_int(v.x));
            if (v.y > 0.f) atomicMax(&tile[t + 1], __float_as_int(v.y));
            if (v.z > 0.f) atomicMax(&tile[t + 2], __float_as_int(v.z));
            if (v.w > 0.f) atomicMax(&tile[t + 3], __float_as_int(v.w));
        }
    }
    __syncthreads();

    if (!ovf) {
        // Normal path: tile (>= 0) IS the answer; no seg read, no memset.
        for (int j = tid; j < RBINS; j += P2_BLOCK) {
            f4 o;
            o.x = __int_as_float(tile[j * 4 + 0]);
            o.y = __int_as_float(tile[j * 4 + 1]);
            o.z = __int_as_float(tile[j * 4 + 2]);
            o.w = __int_as_float(tile[j * 4 + 3]);
            *(f4*)(seg + (size_t)(b0 + j) * 4) = o;
        }
    } else {
        // Overflow path: merge with seg's atomic-accumulated maxes.
        for (int j = tid; j < RBINS; j += P2_BLOCK) {
            f4 s = *(const f4*)(seg + (size_t)(b0 + j) * 4);
            f4 o;
            o.x = fmaxf(__int_as_float(tile[j * 4 + 0]), s.x);
            o.y = fmaxf(__int_as_float(tile[j * 4 + 1]), s.y);
            o.z = fmaxf(__int_as_float(tile[j * 4 + 2]), s.z);
            o.w = fmaxf(__int_as_float(tile[j * 4 + 3]), s.w);
            *(f4*)(seg + (size_t)(b0 + j) * 4) = o;
        }
    }
}

// ---------------- Fallback (round-4 kernel, proven) ----------------
__global__ __launch_bounds__(256) void pfe_scatter_kernel(
    const f4* __restrict__ pc, const float* __restrict__ lim,
    const int* __restrict__ size, f4* __restrict__ pc_masked,
    float* __restrict__ seg, int n) {
    const float l00 = lim[0], l01 = lim[1], l10 = lim[2], l11 = lim[3];
    const int s0 = size[0];
    const float fs0 = (float)size[0], fs1 = (float)size[1];
    const float dx = l01 - l00, dy = l11 - l10;
    const f4 zero = {0.f, 0.f, 0.f, 0.f};

    const int stride = gridDim.x * blockDim.x;
    int base = blockIdx.x * blockDim.x + threadIdx.x;
    for (; base < n; base += 4 * stride) {
        f4 p[4]; bool live[4]; int bin[4];
        #pragma unroll
        for (int u = 0; u < 4; ++u) {
            const int i = base + u * stride;
            live[u] = i < n;
            p[u] = live[u] ? pc[i] : (f4){l00, l10, 0.f, 0.f};
        }
        #pragma unroll
        for (int u = 0; u < 4; ++u) {
            bin[u] = point_bin(p[u], l00, l01, l10, l11, dx, dy, fs0, fs1, s0);
            if (live[u])
                __builtin_nontemporal_store(bin[u] >= 0 ? p[u] : zero,
                                            &pc_masked[base + u * stride]);
        }
        f4 cur[4];
        #pragma unroll
        for (int u = 0; u < 4; ++u)
            if (bin[u] >= 0) cur[u] = *(const f4*)(seg + (size_t)bin[u] * 4);
        #pragma unroll
        for (int u = 0; u < 4; ++u) {
            if (bin[u] < 0) continue;
            dev_atomic_max_filtered(seg + (size_t)bin[u] * 4, p[u], cur[u]);
        }
    }
}

extern "C" void kernel_launch(void* const* d_in, const int* in_sizes, int n_in,
                              void* d_out, int out_size, void* d_ws, size_t ws_size,
                              hipStream_t stream) {
    const f4*    pc  = (const f4*)d_in[0];
    const float* lim = (const float*)d_in[1];
    const int*   sz  = (const int*)d_in[2];

    const int n = in_sizes[0] / 4;             // 8,000,000 points
    float* out       = (float*)d_out;
    float* pc_masked = out;                    // n*4 floats
    float* seg       = out + (size_t)n * 4;    // NBINS*4 floats

    const int nblk = (n + P1_PTS - 1) / P1_PTS;          // 1954
    const size_t tbl_bytes =
        (size_t)(REGIONS + 1) * nblk * sizeof(unsigned); // ~2.0 MB

    // Workspace: bvals f4[cap] | table u32[(REGIONS+1)*nblk] | cursor u32
    long long cap = 0;
    if (ws_size > tbl_bytes + 64)
        cap = (long long)((ws_size - tbl_bytes - 64) / sizeof(f4));
    if (cap > 8100000) cap = 8100000;          // never need more than n

    if (cap >= 6500000 && nblk <= NBLK_MAX) {  // expected masked ~5.43M
        f4*       bvals  = (f4*)d_ws;
        unsigned* table  = (unsigned*)(bvals + cap);
        unsigned* cursor = table + (size_t)(REGIONS + 1) * nblk;

        // Only the 4-byte cursor needs clearing — seg needs NO memset
        // (pass 2 fully overwrites it; overflow path is max-idempotent).
        (void)hipMemsetAsync(cursor, 0, sizeof(unsigned), stream);

        pfe_pass1<<<nblk, P1_BLOCK, 0, stream>>>(
            pc, lim, sz, (f4*)pc_masked, seg, bvals, table, cursor,
            (unsigned)cap, n, nblk);
        pfe_pass2<<<REGIONS, P2_BLOCK, 0, stream>>>(
            bvals, table, lim, sz, cursor, nblk, (unsigned)cap, seg);
    } else {
        (void)hipMemsetAsync(seg, 0, (size_t)NBINS * 4 * sizeof(float), stream);
        pfe_scatter_kernel<<<2048, 256, 0, stream>>>(
            pc, lim, sz, (f4*)pc_masked, seg, n);
    }
}